// Round 12
// baseline (141.349 us; speedup 1.0000x reference)
//
#include <hip/hip_runtime.h>
#include <math.h>

#define J 25
#define NJC 75             // J * CIN
#define NWAVE 4            // waves per block
#define NTHREADS 256
#define NFPW 32            // frames per wave (persistent grid: 512 blocks)

// const-image layout (bf16 element offsets in CWS, per block in LDS)
#define O_A1P  0           // B for P2'', k32-permuted softmax(A1), 1024
#define O_APP  1024        // B for mix, k32-permuted App=A3s@A2s, 1024
#define O_A4B  2048        // A/B for P7, k32-permuted, 1024
#define O_W23  3072        // B for U'=H@W23, k64-permuted, 2 N-tiles, 4096
#define O_W1A  7168        // B for P1', natural k=c-aug, [tile][half][n=d32][j8], 1024
#define O_W4C  8192        // B for P6, k64-permuted, [c][b][j], 256
#define O_B4   8512        // 4 floats (8 bf16 slots)
#define O_BPPF 8576        // 64 fp32 bias in C-reg order [g(4)][half(2)][jj(8)]
#define CWS_SZ 8704

using bf16x2 = __attribute__((ext_vector_type(2))) __bf16;
using bf16x8 = __attribute__((ext_vector_type(8))) __bf16;
using f32x4  = __attribute__((ext_vector_type(4))) float;
using f32x16 = __attribute__((ext_vector_type(16))) float;

__device__ inline bf16x8 zero8() {
    bf16x8 z;
    #pragma unroll
    for (int j = 0; j < 8; j++) z[j] = (__bf16)0.f;
    return z;
}

#if defined(__has_builtin)
#if __has_builtin(__builtin_amdgcn_cvt_pk_bf16_f32)
#define HAVE_PK_BF16 1
#endif
#endif

__device__ inline bf16x2 cvt2(float a, float b) {
#ifdef HAVE_PK_BF16
    return __builtin_amdgcn_cvt_pk_bf16_f32(a, b);
#else
    bf16x2 r; r[0] = (__bf16)a; r[1] = (__bf16)b; return r;
#endif
}
__device__ inline bf16x8 pk8(const f32x16& acc, int st) {
    const int b = 8 * st;
    bf16x8 r;
    #pragma unroll
    for (int p = 0; p < 4; p++) {
        bf16x2 v = cvt2(acc[b + 2 * p], acc[b + 2 * p + 1]);
        r[2 * p] = v[0]; r[2 * p + 1] = v[1];
    }
    return r;
}

// ---------------------------------------------------------------------------
// R12: W23 ALGEBRAIC FOLD on the R8 base (57us champion).
// In-wave overlap is closed (R10 lockstep, R11 skew both regressed: the
// compiler re-schedules hand-interleaves; extra live state only hurts
// allocation).  The chain itself is the last lever: reference has NO relu
// between encoder_g2 and decoder_g1, so
//   A3s.(A2s.H.W2 + b2).W3 + b3 == App.H.(W2@W3) + bpp
// (softmax rows sum to 1 carries b2 through; bpp = W3^T b2 + b3 is already
// in the prologue).  Precompute W23 = W2@W3 (64x64):
//   middle P3->P4->P5 (3 segments, 10 MFMA) becomes
//   U' = H.W23 (8 MFMA) -> HD = relu(App.U' + bpp) (4 MFMA): 2 segments.
// Chain 7 -> 6 segments (-14% latency), +2 MFMA issue (hidden in stalls),
// pack count unchanged (8 pk8).  Plumbing reuses rApp/rB16/hd layouts
// verbatim.  One fewer bf16 intermediate rounding (latent U not rounded).
// Grid/structure identical to R8: persistent 512 blocks, NFPW=32, rolled
// 2-frame loop, launch_bounds(256,2), swapped-P7 epilogue.
// ---------------------------------------------------------------------------
__global__ __launch_bounds__(NTHREADS, 2) void gcn_fused(
    const float* __restrict__ x,
    const float* __restrict__ A1, const float* __restrict__ W1, const float* __restrict__ b1,
    const float* __restrict__ A2, const float* __restrict__ W2, const float* __restrict__ b2,
    const float* __restrict__ A3, const float* __restrict__ W3, const float* __restrict__ b3,
    const float* __restrict__ A4, const float* __restrict__ W4, const float* __restrict__ b4,
    float* __restrict__ out)
{
    __shared__ __align__(16) float  TS[4096];            // prologue scratch (W23f reuse)
    __shared__ __align__(16) __bf16 CWS[CWS_SZ];         // 17408 B

    const int t = threadIdx.x;

    // ================= per-block prologue: const image into CWS ===========
    {
        float* T   = TS;
        float* bpp = T + 3125;
        float* T0 = T;        float* T1 = T + 625;  float* T2 = T + 1250;
        float* T3 = T + 1875; float* T4 = T + 2500;

        if (t < 100) {
            const int m = t / J, i = t % J;
            const float* Asrc = (m == 0) ? A1 : (m == 1) ? A2 : (m == 2) ? A3 : A4;
            float row[J];
            float mx = -1e30f;
            #pragma unroll
            for (int j = 0; j < J; j++) { row[j] = Asrc[i * J + j]; mx = fmaxf(mx, row[j]); }
            float s = 0.f;
            #pragma unroll
            for (int j = 0; j < J; j++) { row[j] = __expf(row[j] - mx); s += row[j]; }
            const float inv = 1.f / s;
            float* dst = T + m * 625 + i * J;
            #pragma unroll
            for (int j = 0; j < J; j++) dst[j] = row[j] * inv;
        }
        if (t < 64) {                                      // bpp = W3^T b2 + b3
            float s = b3[t];
            #pragma unroll
            for (int l = 0; l < 32; l++) s += W3[l * 64 + t] * b2[l];
            bpp[t] = s;
        }
        __syncthreads();

        for (int idx = t; idx < 625; idx += 256) {        // App = A3s @ A2s
            const int i = idx / J, jj = idx % J;
            float s = 0.f;
            #pragma unroll
            for (int k = 0; k < J; k++) s += T2[i * J + k] * T1[k * J + jj];
            T4[idx] = s;
        }
        __syncthreads();

        // ---- A1P, App, A4b (all k32-permuted) ----
        for (int i = t; i < 1024; i += 256) {
            const int b = i >> 8, n = (i >> 3) & 31, jj = i & 7;
            const int s = b >> 1, h = b & 1, r = 8 * s + jj;
            const int k32 = (r & 3) + 8 * (r >> 2) + 4 * h;
            const bool ok = (k32 < J && n < J);
            CWS[O_A1P + i] = (__bf16)(ok ? T0[n * J + k32] : 0.f);
            CWS[O_APP + i] = (__bf16)(ok ? T4[n * J + k32] : 0.f);
            CWS[O_A4B + i] = (__bf16)(ok ? T3[n * J + k32] : 0.f);
        }
        // ---- W1A (B for P1'): [tile][half][n=d32][j8], k = 8*half+j natural;
        //      k<3 -> W1[k][d]; k==3 -> b1[d]; else 0 ----
        for (int i = t; i < 1024; i += 256) {
            const int tile = i >> 9, rr = i & 511, hf_ = rr >> 8, n = (rr >> 3) & 31, jj = rr & 7;
            const int k = 8 * hf_ + jj;
            const int d = tile * 32 + n;
            float v = 0.f;
            if (k < 3) v = W1[k * 64 + d];
            else if (k == 3) v = b1[d];
            CWS[O_W1A + i] = (__bf16)v;
        }
        // ---- W4c (k64-perm): [c][b][j] = W4[d64][c] ----
        {
            const int c = t >> 6, b = (t >> 3) & 7, jj = t & 7;
            const int s = b >> 1, h = b & 1, r = 8 * (s & 1) + jj;
            const int d = 32 * (s >> 1) + (r & 3) + 8 * (r >> 2) + 4 * h;
            CWS[O_W4C + t] = (c < 3) ? (__bf16)W4[d * 3 + c] : (__bf16)0.f;
        }
        // ---- fp32 bias tables (reads bpp -- must precede W23f overwrite) ----
        {
            float* fwB = (float*)(CWS + O_BPPF);
            if (t < 64) {
                const int g = t >> 4, h = (t >> 3) & 1, jj = t & 7;
                const int tt = g >> 1, st = g & 1;
                const int row32 = (jj & 3) + 16 * st + 8 * (jj >> 2) + 4 * h;
                fwB[t] = bpp[tt * 32 + row32];
            }
            float* fb4 = (float*)(CWS + O_B4);
            if (t >= 64 && t < 68) fb4[t - 64] = (t < 67) ? b4[t - 64] : 0.f;
        }
        __syncthreads();   // T/bpp consumed; TS free for W23f

        // ---- W23f = W2 @ W3 (64x64 fp32) into TS ----
        for (int idx = t; idx < 4096; idx += 256) {
            const int d = idx >> 6, dp = idx & 63;
            float s = 0.f;
            #pragma unroll
            for (int l = 0; l < 32; l++) s += W2[d * 32 + l] * W3[l * 64 + dp];
            TS[idx] = s;
        }
        __syncthreads();

        // ---- W23T (B for U', k64-perm over d, 2 N-tiles of d') ----
        for (int i = t; i < 4096; i += 256) {
            const int tile = i >> 11, rr = i & 2047;
            const int b = rr >> 8, n = (rr >> 3) & 31, jj = rr & 7;
            const int s = b >> 1, h = b & 1, r = 8 * (s & 1) + jj;
            const int d = 32 * (s >> 1) + (r & 3) + 8 * (r >> 2) + 4 * h;
            CWS[O_W23 + i] = (__bf16)TS[d * 64 + tile * 32 + n];
        }
        __syncthreads();   // CWS final
    }

    // ================= main fused pipeline ================================
    const int w = t >> 6, lane = t & 63, ln = lane & 31, half = lane >> 5;
    const int fo = ln * 8;

    const long fbase = ((long)blockIdx.x * NWAVE + w) * NFPW;

    // wave-uniform scalar base pointers (advanced per pair on SALU)
    const float* xp = x + fbase * NJC;        // next PAIR to prefetch from
    float* op = out + fbase * NJC;            // this pair's output base

    const bool xact = (lane < J);             // X-load lanes (implies half0)
    const int xoff = lane * 3;

    // ---- prologue: prefetch pair 0 (frames 0,1) into named registers
    float xA0 = 0.f, xA1 = 0.f, xA2 = 0.f;    // frame 2p
    float xB0 = 0.f, xB1 = 0.f, xB2 = 0.f;    // frame 2p+1
    if (xact) {
        const float* q = xp + xoff;
        xA0 = q[0]; xA1 = q[1]; xA2 = q[2];
        xB0 = q[NJC + 0]; xB1 = q[NJC + 1]; xB2 = q[NJC + 2];
    }
    xp += 2 * NJC;

    // ---- persistent register frags
    bf16x8 rA1P[2], rApp[2], rA4b[2], rW1A[2], rW23[8], rW4[4];
    #pragma unroll
    for (int ks = 0; ks < 2; ks++) {
        rA1P[ks] = *(const bf16x8*)&CWS[O_A1P + (2 * ks + half) * 256 + fo];
        rApp[ks] = *(const bf16x8*)&CWS[O_APP + (2 * ks + half) * 256 + fo];
        rA4b[ks] = *(const bf16x8*)&CWS[O_A4B + (2 * ks + half) * 256 + fo];
        rW1A[ks] = *(const bf16x8*)&CWS[O_W1A + ks * 512 + half * 256 + fo];
    }
    #pragma unroll
    for (int tile = 0; tile < 2; tile++)
        #pragma unroll
        for (int ks = 0; ks < 4; ks++)
            rW23[tile * 4 + ks] =
                *(const bf16x8*)&CWS[O_W23 + tile * 2048 + (half + 2 * ks) * 256 + fo];
    #pragma unroll
    for (int ks = 0; ks < 4; ks++) {
        rW4[ks] = zero8();
        if (ln < 3) rW4[ks] = *(const bf16x8*)&CWS[O_W4C + ln * 64 + (half + 2 * ks) * 8];
    }
    // mix-stage bias (bpp) as MFMA C-operand, C layout rows=d' (per tile)
    f32x16 rB16[2];
    {
        const float* fwB = (const float*)(CWS + O_BPPF);
        #pragma unroll
        for (int tt = 0; tt < 2; tt++)
            #pragma unroll
            for (int st = 0; st < 2; st++) {
                f32x4 qa = *(const f32x4*)&fwB[32 * tt + 16 * st + 8 * half + 0];
                f32x4 qb = *(const f32x4*)&fwB[32 * tt + 16 * st + 8 * half + 4];
                #pragma unroll
                for (int j = 0; j < 4; j++) {
                    rB16[tt][8 * st + j]     = qa[j];
                    rB16[tt][8 * st + 4 + j] = qb[j];
                }
            }
    }
    // b4 as 3 wave-uniform floats (LDS broadcast; plain loads -- R6 lesson:
    // never pass floats through the i32-typed readfirstlane builtin)
    const float* fb4 = (const float*)(CWS + O_B4);
    const float b40 = fb4[0], b41 = fb4[1], b42 = fb4[2];

    // ---- shared zero accumulator (MFMA allows D != C)
    f32x16 Z;
    #pragma unroll
    for (int z = 0; z < 16; z++) Z[z] = 0.f;

    const bool do_store = (lane < J);   // loop-invariant store mask (half0 only)

    // ---- one frame, register-only (P1'..P7 + store); xa pre-packed
    auto frame = [&](bf16x8 xa, float* opp) {
        // P1': G = Xaug @ W1aug
        f32x16 accG0 = __builtin_amdgcn_mfma_f32_32x32x16_bf16(xa, rW1A[0], Z, 0, 0, 0);
        f32x16 accG1 = __builtin_amdgcn_mfma_f32_32x32x16_bf16(xa, rW1A[1], Z, 0, 0, 0);
        bf16x8 ga0 = pk8(accG0, 0), ga1 = pk8(accG0, 1);
        bf16x8 ga2 = pk8(accG1, 0), ga3 = pk8(accG1, 1);

        // P2'': H = relu(A1s @ G)  (b1 folded via ones-column)
        bf16x8 hf[4];
        {
            f32x16 accH0 = __builtin_amdgcn_mfma_f32_32x32x16_bf16(ga0, rA1P[0], Z, 0, 0, 0);
            accH0 = __builtin_amdgcn_mfma_f32_32x32x16_bf16(ga1, rA1P[1], accH0, 0, 0, 0);
            f32x16 accH1 = __builtin_amdgcn_mfma_f32_32x32x16_bf16(ga2, rA1P[0], Z, 0, 0, 0);
            accH1 = __builtin_amdgcn_mfma_f32_32x32x16_bf16(ga3, rA1P[1], accH1, 0, 0, 0);
            #pragma unroll
            for (int z = 0; z < 16; z++) {
                accH0[z] = fmaxf(accH0[z], 0.f);
                accH1[z] = fmaxf(accH1[z], 0.f);
            }
            hf[0] = pk8(accH0, 0); hf[1] = pk8(accH0, 1);
            hf[2] = pk8(accH1, 0); hf[3] = pk8(accH1, 1);
        }

        // U' = H @ W23  (K=64, 2 N-tiles of d') -> C col=d', rows=i
        f32x16 accU0 = __builtin_amdgcn_mfma_f32_32x32x16_bf16(hf[0], rW23[0], Z, 0, 0, 0);
        f32x16 accU1 = __builtin_amdgcn_mfma_f32_32x32x16_bf16(hf[0], rW23[4], Z, 0, 0, 0);
        #pragma unroll
        for (int s = 1; s < 4; s++) {
            accU0 = __builtin_amdgcn_mfma_f32_32x32x16_bf16(hf[s], rW23[s], accU0, 0, 0, 0);
            accU1 = __builtin_amdgcn_mfma_f32_32x32x16_bf16(hf[s], rW23[4 + s], accU1, 0, 0, 0);
        }
        bf16x8 uw0 = pk8(accU0, 0), uw1 = pk8(accU0, 1);
        bf16x8 uw2 = pk8(accU1, 0), uw3 = pk8(accU1, 1);

        // HD = relu(App @ U' + bpp)  (K=i 2 steps per tile) -> col=i', rows=d'
        bf16x8 hd[4];
        {
            f32x16 a0 = __builtin_amdgcn_mfma_f32_32x32x16_bf16(uw0, rApp[0], rB16[0], 0, 0, 0);
            a0 = __builtin_amdgcn_mfma_f32_32x32x16_bf16(uw1, rApp[1], a0, 0, 0, 0);
            f32x16 a1 = __builtin_amdgcn_mfma_f32_32x32x16_bf16(uw2, rApp[0], rB16[1], 0, 0, 0);
            a1 = __builtin_amdgcn_mfma_f32_32x32x16_bf16(uw3, rApp[1], a1, 0, 0, 0);
            #pragma unroll
            for (int z = 0; z < 16; z++) {
                a0[z] = fmaxf(a0[z], 0.f);
                a1[z] = fmaxf(a1[z], 0.f);
            }
            hd[0] = pk8(a0, 0); hd[1] = pk8(a0, 1);
            hd[2] = pk8(a1, 0); hd[3] = pk8(a1, 1);
        }

        // P6: P = HD @ W4 (K=64) -> C lane=c, rows=i'
        f32x16 accP = __builtin_amdgcn_mfma_f32_32x32x16_bf16(hd[0], rW4[0], Z, 0, 0, 0);
        #pragma unroll
        for (int s = 1; s < 4; s++)
            accP = __builtin_amdgcn_mfma_f32_32x32x16_bf16(hd[s], rW4[s], accP, 0, 0, 0);
        bf16x8 pf[2] = { pk8(accP, 0), pk8(accP, 1) };

        // P7 (SWAPPED): out^T -> C col=lane=i'' (25 lanes), rows=c
        f32x16 accO = __builtin_amdgcn_mfma_f32_32x32x16_bf16(pf[0], rA4b[0], Z, 0, 0, 0);
        accO = __builtin_amdgcn_mfma_f32_32x32x16_bf16(pf[1], rA4b[1], accO, 0, 0, 0);
        if (do_store) {
            opp[lane * 3 + 0] = accO[0] + b40;
            opp[lane * 3 + 1] = accO[1] + b41;
            opp[lane * 3 + 2] = accO[2] + b42;
        }
    };

    // ---- ROLLED steady-state loop: 2 frames/iter, static buffer parity
    #pragma unroll 1
    for (int fi = 0; fi < NFPW; fi += 2) {
        // frame A (fi): pack xa, then recycle xA regs for prefetch
        bf16x8 xaA = zero8();
        if (xact) {
            xaA[0] = (__bf16)xA0; xaA[1] = (__bf16)xA1;
            xaA[2] = (__bf16)xA2; xaA[3] = (__bf16)1.f;
        }
        bf16x8 xaB = zero8();
        if (xact) {
            xaB[0] = (__bf16)xB0; xaB[1] = (__bf16)xB1;
            xaB[2] = (__bf16)xB2; xaB[3] = (__bf16)1.f;
        }
        // prefetch next pair
        if (fi + 2 < NFPW && xact) {
            const float* q = xp + xoff;
            xA0 = q[0]; xA1 = q[1]; xA2 = q[2];
            xB0 = q[NJC + 0]; xB1 = q[NJC + 1]; xB2 = q[NJC + 2];
        }
        xp += 2 * NJC;

        frame(xaA, op);
        frame(xaB, op + NJC);
        op += 2 * NJC;
    }
}

// ---------------------------------------------------------------------------
extern "C" void kernel_launch(void* const* d_in, const int* in_sizes, int n_in,
                              void* d_out, int out_size, void* d_ws, size_t ws_size,
                              hipStream_t stream)
{
    const float* x  = (const float*)d_in[0];
    const float* A1 = (const float*)d_in[1];
    const float* W1 = (const float*)d_in[2];
    const float* b1 = (const float*)d_in[3];
    const float* A2 = (const float*)d_in[4];
    const float* W2 = (const float*)d_in[5];
    const float* b2 = (const float*)d_in[6];
    const float* A3 = (const float*)d_in[7];
    const float* W3 = (const float*)d_in[8];
    const float* b3 = (const float*)d_in[9];
    const float* A4 = (const float*)d_in[10];
    const float* W4 = (const float*)d_in[11];
    const float* b4 = (const float*)d_in[12];
    float* out = (float*)d_out;
    (void)d_ws; (void)ws_size;

    const int NT = in_sizes[0] / NJC;                 // 65536
    const int nblocks = NT / (NWAVE * NFPW);          // 512 = 2 blocks/CU

    gcn_fused<<<nblocks, NTHREADS, 0, stream>>>(
        x, A1, W1, b1, A2, W2, b2, A3, W3, b3, A4, W4, b4, out);
}

// Round 13
// 134.197 us; speedup vs baseline: 1.0533x; 1.0533x over previous
//
#include <hip/hip_runtime.h>
#include <math.h>

#define J 25
#define NJC 75             // J * CIN
#define NWAVE 4            // waves per block
#define NTHREADS 256
#define NFPW 32            // frames per wave (persistent grid: 512 blocks)

// const-image layout (bf16 element offsets in CWS, per block in LDS)
#define O_A1P  0           // B for P2'', k32-permuted softmax(A1), 1024
#define O_APP  1024        // B for P4, k32-permuted, 1024
#define O_A4B  2048        // A/B for P7, k32-permuted, 1024
#define O_W2T  3072        // B for P3, k64-permuted, 2048
#define O_W3T  5120        // A for P5, k32-permuted, 2 M-tiles, 2048
#define O_W1A  7168        // B for P1', natural k=c-aug, [tile][half][n=d32][j8], 1024
#define O_W4C  8192        // B for P6, k64-permuted, [c][b][j], 256
#define O_B4   8512        // 4 floats (8 bf16 slots)
#define O_BPPF 8576        // 64 fp32 bias in C-reg order [g(4)][half(2)][jj(8)]
#define CWS_SZ 8704

using bf16x2 = __attribute__((ext_vector_type(2))) __bf16;
using bf16x8 = __attribute__((ext_vector_type(8))) __bf16;
using f32x4  = __attribute__((ext_vector_type(4))) float;
using f32x16 = __attribute__((ext_vector_type(16))) float;

__device__ inline bf16x8 zero8() {
    bf16x8 z;
    #pragma unroll
    for (int j = 0; j < 8; j++) z[j] = (__bf16)0.f;
    return z;
}

#if defined(__has_builtin)
#if __has_builtin(__builtin_amdgcn_cvt_pk_bf16_f32)
#define HAVE_PK_BF16 1
#endif
#endif

__device__ inline bf16x2 cvt2(float a, float b) {
#ifdef HAVE_PK_BF16
    return __builtin_amdgcn_cvt_pk_bf16_f32(a, b);
#else
    bf16x2 r; r[0] = (__bf16)a; r[1] = (__bf16)b; return r;
#endif
}
__device__ inline bf16x8 pk8(const f32x16& acc, int st) {
    const int b = 8 * st;
    bf16x8 r;
    #pragma unroll
    for (int p = 0; p < 4; p++) {
        bf16x2 v = cvt2(acc[b + 2 * p], acc[b + 2 * p + 1]);
        r[2 * p] = v[0]; r[2 * p + 1] = v[1];
    }
    return r;
}

// ---------------------------------------------------------------------------
// R13: PHASE-DESYNC probe on the R8 base (57us champion; R12 fold reverted).
// Ledger: R8 per-SIMD = 2137 cyc/frame at 2 waves/SIMD; bottom-up one-wave
// chain latency estimate (6-7 segments x [dep-MFMA burst ~128 + acc drain
// ~60 + pack ~40 + hazards]) ~= 1900-2100 cyc == the per-SIMD number -> the
// two co-resident waves give ZERO mutual overlap.  Mechanism: both blocks
// run identical code from the same dispatch instant -> MFMA bursts collide,
// drain-stall windows coincide; 54% idle = both waves stalled together.
// Probe: after the prologue, blocks with (blockIdx ^ blockIdx>>8)&1 (covers
// both plausible co-residency pairings (2c,2c+1) and (c,c+256)) sleep
// ~2048 cyc (4 x s_sleep(8)) -- half a frame -- so one wave's drains fall
// under the other's bursts.  One-time ~0.9us cost; all else byte-identical
// to R8 (persistent 512 blocks, NFPW=32, rolled 2-frame loop, rB16
// persistent C-in, swapped-P7 epilogue, plain b4 loads).
// ---------------------------------------------------------------------------
__global__ __launch_bounds__(NTHREADS, 2) void gcn_fused(
    const float* __restrict__ x,
    const float* __restrict__ A1, const float* __restrict__ W1, const float* __restrict__ b1,
    const float* __restrict__ A2, const float* __restrict__ W2, const float* __restrict__ b2,
    const float* __restrict__ A3, const float* __restrict__ W3, const float* __restrict__ b3,
    const float* __restrict__ A4, const float* __restrict__ W4, const float* __restrict__ b4,
    float* __restrict__ out)
{
    __shared__ __align__(16) float  TS[3189];            // prologue scratch
    __shared__ __align__(16) __bf16 CWS[CWS_SZ];         // 17408 B

    const int t = threadIdx.x;

    // ================= per-block prologue: const image into CWS ===========
    {
        float* T   = TS;
        float* bpp = T + 3125;
        float* T0 = T;        float* T1 = T + 625;  float* T2 = T + 1250;
        float* T3 = T + 1875; float* T4 = T + 2500;

        if (t < 100) {
            const int m = t / J, i = t % J;
            const float* Asrc = (m == 0) ? A1 : (m == 1) ? A2 : (m == 2) ? A3 : A4;
            float row[J];
            float mx = -1e30f;
            #pragma unroll
            for (int j = 0; j < J; j++) { row[j] = Asrc[i * J + j]; mx = fmaxf(mx, row[j]); }
            float s = 0.f;
            #pragma unroll
            for (int j = 0; j < J; j++) { row[j] = __expf(row[j] - mx); s += row[j]; }
            const float inv = 1.f / s;
            float* dst = T + m * 625 + i * J;
            #pragma unroll
            for (int j = 0; j < J; j++) dst[j] = row[j] * inv;
        }
        if (t < 64) {                                      // bpp = W3^T b2 + b3
            float s = b3[t];
            #pragma unroll
            for (int l = 0; l < 32; l++) s += W3[l * 64 + t] * b2[l];
            bpp[t] = s;
        }
        __syncthreads();

        for (int idx = t; idx < 625; idx += 256) {        // App = A3s @ A2s
            const int i = idx / J, jj = idx % J;
            float s = 0.f;
            #pragma unroll
            for (int k = 0; k < J; k++) s += T2[i * J + k] * T1[k * J + jj];
            T4[idx] = s;
        }
        __syncthreads();

        // ---- A1P, App, A4b (all k32-permuted) ----
        for (int i = t; i < 1024; i += 256) {
            const int b = i >> 8, n = (i >> 3) & 31, jj = i & 7;
            const int s = b >> 1, h = b & 1, r = 8 * s + jj;
            const int k32 = (r & 3) + 8 * (r >> 2) + 4 * h;
            const bool ok = (k32 < J && n < J);
            CWS[O_A1P + i] = (__bf16)(ok ? T0[n * J + k32] : 0.f);
            CWS[O_APP + i] = (__bf16)(ok ? T4[n * J + k32] : 0.f);
            CWS[O_A4B + i] = (__bf16)(ok ? T3[n * J + k32] : 0.f);
        }
        // ---- W2T (k64-perm) | W3T (k32-perm, 2 tiles) ----
        for (int i = t; i < 2048; i += 256) {
            {
                const int b = i >> 8, n = (i >> 3) & 31, jj = i & 7;
                const int s = b >> 1, h = b & 1, r = 8 * (s & 1) + jj;
                const int d = 32 * (s >> 1) + (r & 3) + 8 * (r >> 2) + 4 * h;
                CWS[O_W2T + i] = (__bf16)W2[d * 32 + n];
            }
            {
                const int tt = i >> 10, rr = i & 1023;
                const int b = rr >> 8, m = (rr >> 3) & 31, jj = rr & 7;
                const int s = b >> 1, h = b & 1, r = 8 * s + jj;
                const int l = (r & 3) + 8 * (r >> 2) + 4 * h;
                CWS[O_W3T + i] = (__bf16)W3[l * 64 + tt * 32 + m];
            }
        }
        // ---- W1A (B for P1'): [tile][half][n=d32][j8], k = 8*half+j natural;
        //      k<3 -> W1[k][d]; k==3 -> b1[d]; else 0 ----
        for (int i = t; i < 1024; i += 256) {
            const int tile = i >> 9, rr = i & 511, hf_ = rr >> 8, n = (rr >> 3) & 31, jj = rr & 7;
            const int k = 8 * hf_ + jj;
            const int d = tile * 32 + n;
            float v = 0.f;
            if (k < 3) v = W1[k * 64 + d];
            else if (k == 3) v = b1[d];
            CWS[O_W1A + i] = (__bf16)v;
        }
        // ---- W4c (k64-perm): [c][b][j] = W4[d64][c] ----
        {
            const int c = t >> 6, b = (t >> 3) & 7, jj = t & 7;
            const int s = b >> 1, h = b & 1, r = 8 * (s & 1) + jj;
            const int d = 32 * (s >> 1) + (r & 3) + 8 * (r >> 2) + 4 * h;
            CWS[O_W4C + t] = (c < 3) ? (__bf16)W4[d * 3 + c] : (__bf16)0.f;
        }
        // ---- fp32 bias tables ----
        {
            float* fwB = (float*)(CWS + O_BPPF);
            if (t < 64) {
                const int g = t >> 4, h = (t >> 3) & 1, jj = t & 7;
                const int tt = g >> 1, st = g & 1;
                const int row32 = (jj & 3) + 16 * st + 8 * (jj >> 2) + 4 * h;
                fwB[t] = bpp[tt * 32 + row32];
            }
            float* fb4 = (float*)(CWS + O_B4);
            if (t >= 64 && t < 68) fb4[t - 64] = (t < 67) ? b4[t - 64] : 0.f;
        }
        __syncthreads();   // CWS final
    }

    // ---- PHASE DESYNC: stagger co-resident blocks by ~half a frame.
    //      (blockIdx ^ blockIdx>>8)&1 differs for both plausible pairings
    //      (2c,2c+1) and (c,c+256).  4 x s_sleep(8) ~= 2048 cyc, one-time.
    if ((blockIdx.x ^ (blockIdx.x >> 8)) & 1) {
        #pragma unroll
        for (int i = 0; i < 4; i++) __builtin_amdgcn_s_sleep(8);
    }

    // ================= main fused pipeline ================================
    const int w = t >> 6, lane = t & 63, ln = lane & 31, half = lane >> 5;
    const int fo = ln * 8;

    const long fbase = ((long)blockIdx.x * NWAVE + w) * NFPW;

    // wave-uniform scalar base pointers (advanced per pair on SALU)
    const float* xp = x + fbase * NJC;        // next PAIR to prefetch from
    float* op = out + fbase * NJC;            // this pair's output base

    const bool xact = (lane < J);             // X-load lanes (implies half0)
    const int xoff = lane * 3;

    // ---- prologue: prefetch pair 0 (frames 0,1) into named registers
    float xA0 = 0.f, xA1 = 0.f, xA2 = 0.f;    // frame 2p
    float xB0 = 0.f, xB1 = 0.f, xB2 = 0.f;    // frame 2p+1
    if (xact) {
        const float* q = xp + xoff;
        xA0 = q[0]; xA1 = q[1]; xA2 = q[2];
        xB0 = q[NJC + 0]; xB1 = q[NJC + 1]; xB2 = q[NJC + 2];
    }
    xp += 2 * NJC;

    // ---- persistent register frags
    bf16x8 rA1P[2], rApp[2], rA4b[2], rW1A[2], rW2[4], rW3[4], rW4[4];
    #pragma unroll
    for (int ks = 0; ks < 2; ks++) {
        rA1P[ks] = *(const bf16x8*)&CWS[O_A1P + (2 * ks + half) * 256 + fo];
        rApp[ks] = *(const bf16x8*)&CWS[O_APP + (2 * ks + half) * 256 + fo];
        rA4b[ks] = *(const bf16x8*)&CWS[O_A4B + (2 * ks + half) * 256 + fo];
        rW1A[ks] = *(const bf16x8*)&CWS[O_W1A + ks * 512 + half * 256 + fo];
    }
    #pragma unroll
    for (int ks = 0; ks < 4; ks++)
        rW2[ks] = *(const bf16x8*)&CWS[O_W2T + (half + 2 * ks) * 256 + fo];
    #pragma unroll
    for (int tt = 0; tt < 2; tt++)
        #pragma unroll
        for (int ks = 0; ks < 2; ks++)
            rW3[tt * 2 + ks] = *(const bf16x8*)&CWS[O_W3T + tt * 1024 + (half + 2 * ks) * 256 + fo];
    #pragma unroll
    for (int ks = 0; ks < 4; ks++) {
        rW4[ks] = zero8();
        if (ln < 3) rW4[ks] = *(const bf16x8*)&CWS[O_W4C + ln * 64 + (half + 2 * ks) * 8];
    }
    // P5 bias as MFMA C-operand, C layout (persistent, R5/R8-proven)
    f32x16 rB16[2];
    {
        const float* fwB = (const float*)(CWS + O_BPPF);
        #pragma unroll
        for (int tt = 0; tt < 2; tt++)
            #pragma unroll
            for (int st = 0; st < 2; st++) {
                f32x4 qa = *(const f32x4*)&fwB[32 * tt + 16 * st + 8 * half + 0];
                f32x4 qb = *(const f32x4*)&fwB[32 * tt + 16 * st + 8 * half + 4];
                #pragma unroll
                for (int j = 0; j < 4; j++) {
                    rB16[tt][8 * st + j]     = qa[j];
                    rB16[tt][8 * st + 4 + j] = qb[j];
                }
            }
    }
    // b4 as 3 wave-uniform floats (LDS broadcast; plain loads -- R6 lesson:
    // never pass floats through the i32-typed readfirstlane builtin)
    const float* fb4 = (const float*)(CWS + O_B4);
    const float b40 = fb4[0], b41 = fb4[1], b42 = fb4[2];

    // ---- shared zero accumulator (MFMA allows D != C)
    f32x16 Z;
    #pragma unroll
    for (int z = 0; z < 16; z++) Z[z] = 0.f;

    const bool do_store = (lane < J);   // loop-invariant store mask (half0 only)

    // ---- one frame, register-only (P1'..P7 + store); xa pre-packed
    auto frame = [&](bf16x8 xa, float* opp) {
        // P1': G = Xaug @ W1aug
        f32x16 accG0 = __builtin_amdgcn_mfma_f32_32x32x16_bf16(xa, rW1A[0], Z, 0, 0, 0);
        f32x16 accG1 = __builtin_amdgcn_mfma_f32_32x32x16_bf16(xa, rW1A[1], Z, 0, 0, 0);
        bf16x8 ga0 = pk8(accG0, 0), ga1 = pk8(accG0, 1);
        bf16x8 ga2 = pk8(accG1, 0), ga3 = pk8(accG1, 1);

        // P2'': H = A1s @ G (relu; b1 folded via ones-column)
        bf16x8 hf[4];
        {
            f32x16 accH0 = __builtin_amdgcn_mfma_f32_32x32x16_bf16(ga0, rA1P[0], Z, 0, 0, 0);
            accH0 = __builtin_amdgcn_mfma_f32_32x32x16_bf16(ga1, rA1P[1], accH0, 0, 0, 0);
            f32x16 accH1 = __builtin_amdgcn_mfma_f32_32x32x16_bf16(ga2, rA1P[0], Z, 0, 0, 0);
            accH1 = __builtin_amdgcn_mfma_f32_32x32x16_bf16(ga3, rA1P[1], accH1, 0, 0, 0);
            #pragma unroll
            for (int z = 0; z < 16; z++) {
                accH0[z] = fmaxf(accH0[z], 0.f);
                accH1[z] = fmaxf(accH1[z], 0.f);
            }
            hf[0] = pk8(accH0, 0); hf[1] = pk8(accH0, 1);
            hf[2] = pk8(accH1, 0); hf[3] = pk8(accH1, 1);
        }

        // P3: U = H @ W2 (K=64) -> C lane=l, rows=i
        f32x16 accU = __builtin_amdgcn_mfma_f32_32x32x16_bf16(hf[0], rW2[0], Z, 0, 0, 0);
        #pragma unroll
        for (int s = 1; s < 4; s++)
            accU = __builtin_amdgcn_mfma_f32_32x32x16_bf16(hf[s], rW2[s], accU, 0, 0, 0);
        bf16x8 uf[2] = { pk8(accU, 0), pk8(accU, 1) };

        // P4: V = App @ U -> lane=i', rows=l
        f32x16 accV = __builtin_amdgcn_mfma_f32_32x32x16_bf16(uf[0], rApp[0], Z, 0, 0, 0);
        accV = __builtin_amdgcn_mfma_f32_32x32x16_bf16(uf[1], rApp[1], accV, 0, 0, 0);
        bf16x8 vf[2] = { pk8(accV, 0), pk8(accV, 1) };

        // P5: HD^T = relu(W3 @ V^T + bpp), bias pre-loaded as C-in
        bf16x8 hd[4];
        #pragma unroll
        for (int tt = 0; tt < 2; tt++) {
            f32x16 acc = __builtin_amdgcn_mfma_f32_32x32x16_bf16(rW3[tt * 2 + 0], vf[0], rB16[tt], 0, 0, 0);
            acc = __builtin_amdgcn_mfma_f32_32x32x16_bf16(rW3[tt * 2 + 1], vf[1], acc, 0, 0, 0);
            #pragma unroll
            for (int z = 0; z < 16; z++) acc[z] = fmaxf(acc[z], 0.f);
            hd[2 * tt]     = pk8(acc, 0);
            hd[2 * tt + 1] = pk8(acc, 1);
        }

        // P6: P = HD @ W4 (K=64) -> C lane=c, rows=i'
        f32x16 accP = __builtin_amdgcn_mfma_f32_32x32x16_bf16(hd[0], rW4[0], Z, 0, 0, 0);
        #pragma unroll
        for (int s = 1; s < 4; s++)
            accP = __builtin_amdgcn_mfma_f32_32x32x16_bf16(hd[s], rW4[s], accP, 0, 0, 0);
        bf16x8 pf[2] = { pk8(accP, 0), pk8(accP, 1) };

        // P7 (SWAPPED): out^T -> C col=lane=i'' (25 lanes), rows=c
        f32x16 accO = __builtin_amdgcn_mfma_f32_32x32x16_bf16(pf[0], rA4b[0], Z, 0, 0, 0);
        accO = __builtin_amdgcn_mfma_f32_32x32x16_bf16(pf[1], rA4b[1], accO, 0, 0, 0);
        if (do_store) {
            opp[lane * 3 + 0] = accO[0] + b40;
            opp[lane * 3 + 1] = accO[1] + b41;
            opp[lane * 3 + 2] = accO[2] + b42;
        }
    };

    // ---- ROLLED steady-state loop: 2 frames/iter, static buffer parity
    #pragma unroll 1
    for (int fi = 0; fi < NFPW; fi += 2) {
        // frame A (fi): pack xa, then recycle xA regs for prefetch
        bf16x8 xaA = zero8();
        if (xact) {
            xaA[0] = (__bf16)xA0; xaA[1] = (__bf16)xA1;
            xaA[2] = (__bf16)xA2; xaA[3] = (__bf16)1.f;
        }
        bf16x8 xaB = zero8();
        if (xact) {
            xaB[0] = (__bf16)xB0; xaB[1] = (__bf16)xB1;
            xaB[2] = (__bf16)xB2; xaB[3] = (__bf16)1.f;
        }
        // prefetch next pair
        if (fi + 2 < NFPW && xact) {
            const float* q = xp + xoff;
            xA0 = q[0]; xA1 = q[1]; xA2 = q[2];
            xB0 = q[NJC + 0]; xB1 = q[NJC + 1]; xB2 = q[NJC + 2];
        }
        xp += 2 * NJC;

        frame(xaA, op);
        frame(xaB, op + NJC);
        op += 2 * NJC;
    }
}

// ---------------------------------------------------------------------------
extern "C" void kernel_launch(void* const* d_in, const int* in_sizes, int n_in,
                              void* d_out, int out_size, void* d_ws, size_t ws_size,
                              hipStream_t stream)
{
    const float* x  = (const float*)d_in[0];
    const float* A1 = (const float*)d_in[1];
    const float* W1 = (const float*)d_in[2];
    const float* b1 = (const float*)d_in[3];
    const float* A2 = (const float*)d_in[4];
    const float* W2 = (const float*)d_in[5];
    const float* b2 = (const float*)d_in[6];
    const float* A3 = (const float*)d_in[7];
    const float* W3 = (const float*)d_in[8];
    const float* b3 = (const float*)d_in[9];
    const float* A4 = (const float*)d_in[10];
    const float* W4 = (const float*)d_in[11];
    const float* b4 = (const float*)d_in[12];
    float* out = (float*)d_out;
    (void)d_ws; (void)ws_size;

    const int NT = in_sizes[0] / NJC;                 // 65536
    const int nblocks = NT / (NWAVE * NFPW);          // 512 = 2 blocks/CU

    gcn_fused<<<nblocks, NTHREADS, 0, stream>>>(
        x, A1, W1, b1, A2, W2, b2, A3, W3, b3, A4, W4, b4, out);
}